// Round 11
// baseline (494.433 us; speedup 1.0000x reference)
//
#include <hip/hip_runtime.h>

// ---------------------------------------------------------------------------
// LRU single step, fused — v12 (5-phase single-pass structure).
//   state = Lambda * x0 + Bn @ u              (complex; stored PLANAR re|im)
//   y     = s_re @ C_re^T - s_im @ C_im^T + u @ D^T
//
// Ladder (lru_main dur / FETCH+WRITE MB):
//  v2 192/196 baseline. v3 fragment-I/O BAD. v4 window>L3 BAD. v5/v6 window
//  BAD. v7 195/196 (2 blk/CU window). v8 reg-pipe NULL. v9 fusion REGRESS.
//  v10 176/189 WIN: nt-LOADS (streams stop thrashing L2 weights).
//  v11 176/189 NULL: rotation+setprio (convoy theory falsified).
// v12 diagnosis: every counter pinned across all scheduling variants ->
//  the 15-phase barrier-drain chain IS the floor. Remove phases:
//  ROWS=16 -> whole state row-block (re|im|u = 1280 cols bf16) fits ONE LDS
//  buffer X[16][1288] (41.2KB, 3 blk/CU, window 123MB < L3). Kernel becomes
//  5 phases / 5 barriers: stage-u -> 4x GEMM-A back-to-back (NO interior
//  barriers, fragments land in disjoint X cols) -> ONE epilogue (x0
//  prefetched at kernel start) -> ONE K=1280 streaming y-GEMM (40 k-steps,
//  compiler free to pipeline) -> store. Wy natural layout [C_re|-C_im|D].
// Kept: nt-loads, linear global I/O, swapped-operand MFMA. Dropped:
//  rotation/setprio (null).
// ---------------------------------------------------------------------------

typedef __attribute__((ext_vector_type(8))) short bf16x8;
typedef __attribute__((ext_vector_type(4))) float f32x4;
typedef unsigned short u16;

#define N_ROWS 32768
#define IN_DIM 256
#define SD 512
#define OUT_DIM 256
#define ROWS 16          // rows (n) per block
#define NTHR 512         // 8 waves
#define XP 1288          // X pitch u16: [s_re 512 | s_im 512 | u 256] + 8 pad
#define YP 260           // y staging pitch in f32

#define MFMA16(a, b, c) __builtin_amdgcn_mfma_f32_16x16x32_bf16(a, b, c, 0, 0, 0)

__device__ __align__(16) float g_lam[2 * SD];            // lam_re | lam_im
__device__ __align__(16) u16   g_W1[1024 * IN_DIM];      // bf16
__device__ __align__(16) u16   g_Wy[OUT_DIM * 1280];     // bf16

__device__ __forceinline__ u16 f2b(float f) {
    union { float f; unsigned int u; } v; v.f = f;
    unsigned int r = v.u + 0x7FFFu + ((v.u >> 16) & 1u);   // RNE
    return (u16)(r >> 16);
}
__device__ __forceinline__ ushort4 f2b4(f32x4 v) {
    ushort4 b;
    b.x = f2b(v[0]); b.y = f2b(v[1]); b.z = f2b(v[2]); b.w = f2b(v[3]);
    return b;
}
__device__ __forceinline__ f32x4 b2f4(ushort4 b) {
    union { float f; unsigned int u; } t0, t1, t2, t3;
    t0.u = (unsigned)b.x << 16; t1.u = (unsigned)b.y << 16;
    t2.u = (unsigned)b.z << 16; t3.u = (unsigned)b.w << 16;
    return f32x4{t0.f, t1.f, t2.f, t3.f};
}

// --- combined prep (single launch) -----------------------------------------
__global__ void prep_all(const float* __restrict__ nu_log,
                         const float* __restrict__ theta_log,
                         const float* __restrict__ gamma_log,
                         const float* __restrict__ B_re, const float* __restrict__ B_im,
                         const float* __restrict__ C_re, const float* __restrict__ C_im,
                         const float* __restrict__ D) {
    int b = blockIdx.x, t = threadIdx.x;
    if (b < 1024) {
        // W1 chunked-planar: rows s*256+[0,128)=Bn_re[h=s*128+j], +[128,256)=Bn_im
        int w = b & 255;
        int h = (b >> 8) * 128 + (w & 127);
        float g = expf(gamma_log[h]);
        const float* src = (w < 128) ? B_re : B_im;
        g_W1[b * IN_DIM + t] = f2b(src[h * IN_DIM + t] * g);
    } else if (b < 1280) {
        // Wy natural: [C_re(512) | -C_im(512) | D(256)]
        int o = b - 1024;
        #pragma unroll
        for (int it = 0; it < 5; ++it) {
            int c = it * 256 + t;
            float v;
            if (c < 512)       v =  C_re[o * SD + c];
            else if (c < 1024) v = -C_im[o * SD + (c - 512)];
            else               v =  D[o * IN_DIM + (c - 1024)];
            g_Wy[(size_t)o * 1280 + c] = f2b(v);
        }
    } else {
        int h = (b - 1280) * 256 + t;          // [0,512)
        float mod = expf(-expf(nu_log[h]));
        float th  = expf(theta_log[h]);
        g_lam[h]      = mod * cosf(th);
        g_lam[SD + h] = mod * sinf(th);
    }
}

// --- main fused kernel ------------------------------------------------------
__global__ __launch_bounds__(NTHR, 6) void lru_main(
    const float* __restrict__ u, const float* __restrict__ x0_re,
    const float* __restrict__ x0_im,
    float* __restrict__ y_out, float* __restrict__ st_out,
    long long st_limit)     // floats available in the state region of d_out
{
    __shared__ __align__(16) u16 X[ROWS * XP];   // 41,216 B -> 3 blk/CU

    const int tid  = threadIdx.x;
    const int wv   = tid >> 6;          // [0,8)
    const int lane = tid & 63;
    const int quad = lane >> 4;
    const int l16  = lane & 15;
    const int kq   = quad * 8;
    const size_t n0 = (size_t)blockIdx.x * ROWS;

    const int Mb = wv * 32;             // wave's M base (256-wide plane)

    // epilogue slot mapping: 2048 slots (16 rows x 128 j4), 4 per thread.
    // x0 prefetch issued NOW (nt): an entire GEMM-A phase of latency cover.
    int en[4], ej[4];
    f32x4 xr[4], xi[4];
    #pragma unroll
    for (int it = 0; it < 4; ++it) {
        int flat = it * NTHR + tid;
        en[it] = flat >> 7; ej[it] = flat & 127;
        size_t roff = (n0 + en[it]) * SD + ej[it] * 4;
        xr[it] = __builtin_nontemporal_load((const f32x4*)(x0_re + roff));
        xi[it] = __builtin_nontemporal_load((const f32x4*)(x0_im + roff));
    }

    // stage u tile -> X cols [1024,1280)  (linear nt f32x4 loads)
    #pragma unroll
    for (int i = 0; i < 2; ++i) {
        int it = tid + i * NTHR;              // 1024 items
        int r = it >> 6, c4 = it & 63;
        f32x4 v = __builtin_nontemporal_load(
            (const f32x4*)(u + (n0 + r) * IN_DIM) + c4);
        *(ushort4*)(&X[r * XP + 1024 + c4 * 4]) = f2b4(v);
    }
    __syncthreads();            // (1) u staged

    // ---- GEMM-A x4, back-to-back, NO interior barriers ------------------
    // chunk s: Bu[M=256(re|im)][n=16] = W1_chunk @ u^T; fragments land in
    // disjoint X columns (re -> s*128+hM, im -> 512+s*128+hM-128).
    #pragma unroll
    for (int s = 0; s < 4; ++s) {
        f32x4 acc[2];
        acc[0] = f32x4{0.f, 0.f, 0.f, 0.f};
        acc[1] = f32x4{0.f, 0.f, 0.f, 0.f};
        const u16* w1b = g_W1 + (size_t)(s * 256 + Mb) * IN_DIM;
        #pragma unroll
        for (int k0 = 0; k0 < IN_DIM; k0 += 32) {
            bf16x8 a0, a1, b;
            a0 = *(const bf16x8*)(w1b + l16 * IN_DIM + k0 + kq);
            a1 = *(const bf16x8*)(w1b + (16 + l16) * IN_DIM + k0 + kq);
            b  = *(const bf16x8*)(&X[l16 * XP + 1024 + k0 + kq]);
            acc[0] = MFMA16(a0, b, acc[0]);
            acc[1] = MFMA16(a1, b, acc[1]);
        }
        #pragma unroll
        for (int ht = 0; ht < 2; ++ht) {
            const int hM  = Mb + ht * 16 + quad * 4;     // [0,256)
            const int col = (hM < 128) ? (s * 128 + hM)
                                       : (512 + s * 128 + (hM - 128));
            *(ushort4*)(&X[l16 * XP + col]) = f2b4(acc[ht]);
        }
    }
    __syncthreads();            // (2) all Bu fragments in X

    // ---- ONE epilogue: state = lam*x0 + Bu over all 512 h ----------------
    #pragma unroll
    for (int it = 0; it < 4; ++it) {
        const int n = en[it], j = ej[it] * 4;            // j in [0,512)
        f32x4 br  = b2f4(*(const ushort4*)(&X[n * XP + j]));
        f32x4 bi  = b2f4(*(const ushort4*)(&X[n * XP + 512 + j]));
        f32x4 lre = *(const f32x4*)(g_lam + j);
        f32x4 lim = *(const f32x4*)(g_lam + SD + j);
        f32x4 sr = lre * xr[it] - lim * xi[it] + br;
        f32x4 si = lre * xi[it] + lim * xr[it] + bi;
        const long long ir = (long long)((n0 + n) * SD + j);
        const long long ii = (long long)N_ROWS * SD + ir;
        if (ir + 3 < st_limit) {
            *(f32x4*)(st_out + ir) = sr;       // cacheable: L3 absorbs
        } else {
            #pragma unroll
            for (int k = 0; k < 4; ++k)
                if (ir + k < st_limit) st_out[ir + k] = sr[k];
        }
        if (ii + 3 < st_limit) {
            *(f32x4*)(st_out + ii) = si;
        } else {
            #pragma unroll
            for (int k = 0; k < 4; ++k)
                if (ii + k < st_limit) st_out[ii + k] = si[k];
        }
        *(ushort4*)(&X[n * XP + j])       = f2b4(sr);
        *(ushort4*)(&X[n * XP + 512 + j]) = f2b4(si);
    }
    __syncthreads();            // (3) X = [s_re | s_im | u] bf16, complete

    // ---- ONE streaming y-GEMM: K = 1280, 40 uninterrupted k-steps --------
    f32x4 accy[2];
    accy[0] = f32x4{0.f, 0.f, 0.f, 0.f};
    accy[1] = f32x4{0.f, 0.f, 0.f, 0.f};
    #pragma unroll
    for (int k0 = 0; k0 < 1280; k0 += 32) {
        bf16x8 a0, a1, b;
        a0 = *(const bf16x8*)(g_Wy + (size_t)(Mb + l16) * 1280 + k0 + kq);
        a1 = *(const bf16x8*)(g_Wy + (size_t)(Mb + 16 + l16) * 1280 + k0 + kq);
        b  = *(const bf16x8*)(&X[l16 * XP + k0 + kq]);
        accy[0] = MFMA16(a0, b, accy[0]);
        accy[1] = MFMA16(a1, b, accy[1]);
    }

    // ---- y: fragments -> f32 LDS (X dead) -> linear store ----------------
    __syncthreads();            // (4) everyone done reading X
    float* Yf = (float*)X;      // [16][YP]  (16*260*4 = 16,640 <= 41,216)
    #pragma unroll
    for (int ht = 0; ht < 2; ++ht) {
        const int col = Mb + ht * 16 + quad * 4;
        *(f32x4*)(&Yf[l16 * YP + col]) = accy[ht];
    }
    __syncthreads();            // (5)
    #pragma unroll
    for (int i = 0; i < 2; ++i) {
        int it = tid + i * NTHR;                  // 1024 items
        int r = it >> 6, c4 = it & 63;
        f32x4 v = *(const f32x4*)(&Yf[r * YP + c4 * 4]);
        *(f32x4*)(y_out + (n0 + r) * OUT_DIM + c4 * 4) = v;
    }
}

extern "C" void kernel_launch(void* const* d_in, const int* in_sizes, int n_in,
                              void* d_out, int out_size, void* d_ws, size_t ws_size,
                              hipStream_t stream) {
    const float* u         = (const float*)d_in[0];
    const float* x0_re     = (const float*)d_in[1];
    const float* x0_im     = (const float*)d_in[2];
    const float* nu_log    = (const float*)d_in[3];
    const float* theta_log = (const float*)d_in[4];
    const float* gamma_log = (const float*)d_in[5];
    const float* B_re      = (const float*)d_in[6];
    const float* B_im      = (const float*)d_in[7];
    const float* C_re      = (const float*)d_in[8];
    const float* C_im      = (const float*)d_in[9];
    const float* D         = (const float*)d_in[10];

    float* y_out  = (float*)d_out;
    float* st_out = y_out + (size_t)N_ROWS * OUT_DIM;
    long long st_limit = (long long)out_size - (long long)N_ROWS * OUT_DIM;

    prep_all<<<1282, 256, 0, stream>>>(nu_log, theta_log, gamma_log,
                                       B_re, B_im, C_re, C_im, D);
    lru_main<<<N_ROWS / ROWS, NTHR, 0, stream>>>(u, x0_re, x0_im,
                                                 y_out, st_out, st_limit);
}

// Round 12
// 403.678 us; speedup vs baseline: 1.2248x; 1.2248x over previous
//
#include <hip/hip_runtime.h>

// ---------------------------------------------------------------------------
// LRU single step — v13: TWO-KERNEL SPLIT.
//   S: state = Lambda*x0 + W1@u  -> st_out (f32, guarded) + g_Xc (bf16)
//   Y: y = Wy @ [s_re|s_im|u]^T  -> pure streaming GEMM, K=1280
//
// Ladder (lru_main dur / FETCH+WRITE MB):
//  v2 192/196. v3 frag-I/O BAD. v4 window>L3 BAD. v5/v6 window BAD.
//  v7 195/196. v8 reg-pipe NULL. v9 fusion REGRESS. v10 176/189 WIN
//  (nt-loads). v11 rotation+setprio NULL. v12 ROWS=16 collapse REGRESS
//  (weight amortization halved, FETCH+52MB).
// v13 diagnosis: the fused barrier-chained phase structure is the floor
//  (~18% issue across ALL schedule variants). Split: kernel Y becomes a
//  pure GEMM (1 staging phase + 40 uninterrupted k-steps, 3 barriers);
//  kernel S sheds y/D-GEMM + Sc writeback (5 barriers, 3 blk/CU, window
//  216MB < L3). Handoff via static g_Xc[32768][1280] bf16 (84MB) so
//  correctness never depends on st_limit. Numerics identical to v10.
// Kept: nt-loads, linear global I/O, swapped-operand MFMA, W1/Wy prepacks.
// ---------------------------------------------------------------------------

typedef __attribute__((ext_vector_type(8))) short bf16x8;
typedef __attribute__((ext_vector_type(4))) float f32x4;
typedef unsigned short u16;

#define N_ROWS 32768
#define IN_DIM 256
#define SD 512
#define OUT_DIM 256
#define ROWS 32          // rows per block (both kernels)
#define NTHR 512         // 8 waves
#define TP 264           // S: tile pitch u16 (256 + 8 pad)
#define XP2 1288         // Y: X pitch u16 (1280 + 8 pad)
#define YP 260           // Y: y staging pitch f32

#define MFMA16(a, b, c) __builtin_amdgcn_mfma_f32_16x16x32_bf16(a, b, c, 0, 0, 0)

__device__ __align__(16) float g_lam[2 * SD];            // lam_re | lam_im
__device__ __align__(16) u16   g_W1[1024 * IN_DIM];      // bf16
__device__ __align__(16) u16   g_Wy[OUT_DIM * 1280];     // bf16
__device__ __align__(16) u16   g_Xc[(size_t)N_ROWS * 1280];  // bf16 [s_re|s_im|u]

__device__ __forceinline__ u16 f2b(float f) {
    union { float f; unsigned int u; } v; v.f = f;
    unsigned int r = v.u + 0x7FFFu + ((v.u >> 16) & 1u);   // RNE
    return (u16)(r >> 16);
}
__device__ __forceinline__ ushort4 f2b4(f32x4 v) {
    ushort4 b;
    b.x = f2b(v[0]); b.y = f2b(v[1]); b.z = f2b(v[2]); b.w = f2b(v[3]);
    return b;
}
__device__ __forceinline__ f32x4 b2f4(ushort4 b) {
    union { float f; unsigned int u; } t0, t1, t2, t3;
    t0.u = (unsigned)b.x << 16; t1.u = (unsigned)b.y << 16;
    t2.u = (unsigned)b.z << 16; t3.u = (unsigned)b.w << 16;
    return f32x4{t0.f, t1.f, t2.f, t3.f};
}

// --- combined prep (single launch) -----------------------------------------
__global__ void prep_all(const float* __restrict__ nu_log,
                         const float* __restrict__ theta_log,
                         const float* __restrict__ gamma_log,
                         const float* __restrict__ B_re, const float* __restrict__ B_im,
                         const float* __restrict__ C_re, const float* __restrict__ C_im,
                         const float* __restrict__ D) {
    int b = blockIdx.x, t = threadIdx.x;
    if (b < 1024) {
        // W1 chunked-planar: rows s*256+[0,128)=Bn_re[h=s*128+j], +[128,256)=Bn_im
        int w = b & 255;
        int h = (b >> 8) * 128 + (w & 127);
        float g = expf(gamma_log[h]);
        const float* src = (w < 128) ? B_re : B_im;
        g_W1[b * IN_DIM + t] = f2b(src[h * IN_DIM + t] * g);
    } else if (b < 1280) {
        // Wy natural: [C_re(512) | -C_im(512) | D(256)]
        int o = b - 1024;
        #pragma unroll
        for (int it = 0; it < 5; ++it) {
            int c = it * 256 + t;
            float v;
            if (c < 512)       v =  C_re[o * SD + c];
            else if (c < 1024) v = -C_im[o * SD + (c - 512)];
            else               v =  D[o * IN_DIM + (c - 1024)];
            g_Wy[(size_t)o * 1280 + c] = f2b(v);
        }
    } else {
        int h = (b - 1280) * 256 + t;          // [0,512)
        float mod = expf(-expf(nu_log[h]));
        float th  = expf(theta_log[h]);
        g_lam[h]      = mod * cosf(th);
        g_lam[SD + h] = mod * sinf(th);
    }
}

// --- kernel S: state --------------------------------------------------------
__global__ __launch_bounds__(NTHR, 6) void lru_state(
    const float* __restrict__ u, const float* __restrict__ x0_re,
    const float* __restrict__ x0_im,
    float* __restrict__ st_out, long long st_limit)
{
    __shared__ __align__(16) u16 SMEM[3 * ROWS * TP];   // 50,688 B -> 3 blk/CU

    u16* Xu  = SMEM;                  // u tile bf16 [32][TP]
    u16* Sc0 = SMEM + ROWS * TP;      // Bu chunk bf16, ping
    u16* Sc1 = SMEM + 2 * ROWS * TP;  // Bu chunk bf16, pong

    const int tid  = threadIdx.x;
    const int wv   = tid >> 6;
    const int lane = tid & 63;
    const int quad = lane >> 4;
    const int l16  = lane & 15;
    const int kq   = quad * 8;
    const size_t n0 = (size_t)blockIdx.x * ROWS;

    const int Mb = wv * 32;

    // linear epilogue mapping: 1024 slots (32 rows x 32 j4)
    int en[2], ej[2];
    #pragma unroll
    for (int it = 0; it < 2; ++it) {
        int flat = it * NTHR + tid;
        en[it] = flat >> 5; ej[it] = flat & 31;
    }

    // prefetch x0 chunk 0 (nt)
    f32x4 xr[2], xi[2];
    #pragma unroll
    for (int it = 0; it < 2; ++it) {
        size_t roff = (n0 + en[it]) * SD + ej[it] * 4;
        xr[it] = __builtin_nontemporal_load((const f32x4*)(x0_re + roff));
        xi[it] = __builtin_nontemporal_load((const f32x4*)(x0_im + roff));
    }

    // stage u -> LDS bf16 AND g_Xc cols [1024,1280)
    #pragma unroll
    for (int i = 0; i < 4; ++i) {
        int it = tid + i * NTHR;              // 2048 items
        int r = it >> 6, c4 = it & 63;
        f32x4 v = __builtin_nontemporal_load(
            (const f32x4*)(u + (n0 + r) * IN_DIM) + c4);
        ushort4 b = f2b4(v);
        *(ushort4*)(&Xu[r * TP + c4 * 4]) = b;
        *(ushort4*)(&g_Xc[(n0 + r) * 1280 + 1024 + c4 * 4]) = b;
    }
    __syncthreads();            // (1) u staged

    for (int s = 0; s < 4; ++s) {
        u16* Sc = (s & 1) ? Sc1 : Sc0;

        // GEMM-A (swapped): Bu[M=256(re|im)][n=32] = W1_chunk @ Xu^T
        f32x4 acc[2][2];
        #pragma unroll
        for (int ht = 0; ht < 2; ++ht)
            #pragma unroll
            for (int nt = 0; nt < 2; ++nt)
                acc[ht][nt] = f32x4{0.f, 0.f, 0.f, 0.f};
        const u16* w1b = g_W1 + (size_t)(s * 256 + Mb) * IN_DIM;
        #pragma unroll
        for (int k0 = 0; k0 < IN_DIM; k0 += 32) {
            bf16x8 a[2], b[2];
            #pragma unroll
            for (int ht = 0; ht < 2; ++ht)
                a[ht] = *(const bf16x8*)(w1b + (ht * 16 + l16) * IN_DIM + k0 + kq);
            #pragma unroll
            for (int nt = 0; nt < 2; ++nt)
                b[nt] = *(const bf16x8*)(&Xu[(nt * 16 + l16) * TP + k0 + kq]);
            #pragma unroll
            for (int ht = 0; ht < 2; ++ht)
                #pragma unroll
                for (int nt = 0; nt < 2; ++nt)
                    acc[ht][nt] = MFMA16(a[ht], b[nt], acc[ht][nt]);
        }
        // fragments -> Sc bf16 (contiguous ushort4)
        #pragma unroll
        for (int ht = 0; ht < 2; ++ht)
            #pragma unroll
            for (int nt = 0; nt < 2; ++nt) {
                const int n  = nt * 16 + l16;
                const int hM = Mb + ht * 16 + quad * 4;
                *(ushort4*)(&Sc[n * TP + hM]) = f2b4(acc[ht][nt]);
            }
        __syncthreads();        // (2..5) Sc complete; prev epi readers done

        // epilogue: state = lam*x0 + Bu -> st_out f32 + g_Xc bf16 (linear)
        #pragma unroll
        for (int it = 0; it < 2; ++it) {
            const int n = en[it], j = ej[it];
            f32x4 br  = b2f4(*(const ushort4*)(&Sc[n * TP + j * 4]));
            f32x4 bi  = b2f4(*(const ushort4*)(&Sc[n * TP + 128 + j * 4]));
            f32x4 lre = *(const f32x4*)(g_lam + s * 128 + j * 4);
            f32x4 lim = *(const f32x4*)(g_lam + SD + s * 128 + j * 4);
            f32x4 sr = lre * xr[it] - lim * xi[it] + br;
            f32x4 si = lre * xi[it] + lim * xr[it] + bi;
            const long long ir = (long long)((n0 + n) * SD + s * 128 + j * 4);
            const long long ii = (long long)N_ROWS * SD + ir;
            if (ir + 3 < st_limit) {
                *(f32x4*)(st_out + ir) = sr;
            } else {
                #pragma unroll
                for (int k = 0; k < 4; ++k)
                    if (ir + k < st_limit) st_out[ir + k] = sr[k];
            }
            if (ii + 3 < st_limit) {
                *(f32x4*)(st_out + ii) = si;
            } else {
                #pragma unroll
                for (int k = 0; k < 4; ++k)
                    if (ii + k < st_limit) st_out[ii + k] = si[k];
            }
            *(ushort4*)(&g_Xc[(n0 + n) * 1280 + s * 128 + j * 4])       = f2b4(sr);
            *(ushort4*)(&g_Xc[(n0 + n) * 1280 + 512 + s * 128 + j * 4]) = f2b4(si);
        }

        // prefetch x0 for next chunk (nt); NO barrier after epi (dbuf)
        if (s < 3) {
            #pragma unroll
            for (int it = 0; it < 2; ++it) {
                size_t roff = (n0 + en[it]) * SD + (s + 1) * 128 + ej[it] * 4;
                xr[it] = __builtin_nontemporal_load((const f32x4*)(x0_re + roff));
                xi[it] = __builtin_nontemporal_load((const f32x4*)(x0_im + roff));
            }
        }
    }
}

// --- kernel Y: pure streaming GEMM  y = Wy @ Xc^T ---------------------------
__global__ __launch_bounds__(NTHR) void lru_y(
    float* __restrict__ y_out)
{
    __shared__ __align__(16) u16 X[ROWS * XP2];   // 82,432 B -> 1 blk/CU

    const int tid  = threadIdx.x;
    const int wv   = tid >> 6;
    const int lane = tid & 63;
    const int quad = lane >> 4;
    const int l16  = lane & 15;
    const int kq   = quad * 8;
    const size_t n0 = (size_t)blockIdx.x * ROWS;

    const int Mb = wv * 32;             // wave's o base

    // stage Xc rows -> LDS (already bf16; linear 16B loads, nt)
    #pragma unroll
    for (int i = 0; i < 10; ++i) {
        int it = tid + i * NTHR;              // 5120 16B-chunks
        int r = it >> 7, c8 = it & 127;       // 128 chunks of 10 u16? no:
        // 1280 u16 per row = 160 16B-chunks; use /160 layout:
        r = it / 160; c8 = it % 160;
        bf16x8 v = __builtin_nontemporal_load(
            (const bf16x8*)(&g_Xc[(n0 + r) * 1280 + c8 * 8]));
        *(bf16x8*)(&X[r * XP2 + c8 * 8]) = v;
    }
    __syncthreads();            // (1) X staged

    // K = 1280, 40 uninterrupted k-steps
    f32x4 accy[2][2];
    #pragma unroll
    for (int ot = 0; ot < 2; ++ot)
        #pragma unroll
        for (int nt = 0; nt < 2; ++nt)
            accy[ot][nt] = f32x4{0.f, 0.f, 0.f, 0.f};
    #pragma unroll
    for (int k0 = 0; k0 < 1280; k0 += 32) {
        bf16x8 a[2], b[2];
        #pragma unroll
        for (int ot = 0; ot < 2; ++ot)
            a[ot] = *(const bf16x8*)(g_Wy + (size_t)(Mb + ot * 16 + l16) * 1280
                                     + k0 + kq);
        #pragma unroll
        for (int nt = 0; nt < 2; ++nt)
            b[nt] = *(const bf16x8*)(&X[(nt * 16 + l16) * XP2 + k0 + kq]);
        #pragma unroll
        for (int ot = 0; ot < 2; ++ot)
            #pragma unroll
            for (int nt = 0; nt < 2; ++nt)
                accy[ot][nt] = MFMA16(a[ot], b[nt], accy[ot][nt]);
    }

    // y: fragments -> f32 LDS (X dead) -> linear store
    __syncthreads();            // (2)
    float* Yf = (float*)X;      // [32][YP] = 33,280 B <= 82,432
    #pragma unroll
    for (int ot = 0; ot < 2; ++ot)
        #pragma unroll
        for (int nt = 0; nt < 2; ++nt) {
            const int n   = nt * 16 + l16;
            const int col = Mb + ot * 16 + quad * 4;
            *(f32x4*)(&Yf[n * YP + col]) = accy[ot][nt];
        }
    __syncthreads();            // (3)
    #pragma unroll
    for (int i = 0; i < 4; ++i) {
        int it = tid + i * NTHR;                  // 2048 items
        int r = it >> 6, c4 = it & 63;
        f32x4 v = *(const f32x4*)(&Yf[r * YP + c4 * 4]);
        *(f32x4*)(y_out + (n0 + r) * OUT_DIM + c4 * 4) = v;
    }
}

extern "C" void kernel_launch(void* const* d_in, const int* in_sizes, int n_in,
                              void* d_out, int out_size, void* d_ws, size_t ws_size,
                              hipStream_t stream) {
    const float* u         = (const float*)d_in[0];
    const float* x0_re     = (const float*)d_in[1];
    const float* x0_im     = (const float*)d_in[2];
    const float* nu_log    = (const float*)d_in[3];
    const float* theta_log = (const float*)d_in[4];
    const float* gamma_log = (const float*)d_in[5];
    const float* B_re      = (const float*)d_in[6];
    const float* B_im      = (const float*)d_in[7];
    const float* C_re      = (const float*)d_in[8];
    const float* C_im      = (const float*)d_in[9];
    const float* D         = (const float*)d_in[10];

    float* y_out  = (float*)d_out;
    float* st_out = y_out + (size_t)N_ROWS * OUT_DIM;
    long long st_limit = (long long)out_size - (long long)N_ROWS * OUT_DIM;

    prep_all<<<1282, 256, 0, stream>>>(nu_log, theta_log, gamma_log,
                                       B_re, B_im, C_re, C_im, D);
    lru_state<<<N_ROWS / ROWS, NTHR, 0, stream>>>(u, x0_re, x0_im,
                                                  st_out, st_limit);
    lru_y<<<N_ROWS / ROWS, NTHR, 0, stream>>>(y_out);
}

// Round 13
// 350.914 us; speedup vs baseline: 1.4090x; 1.1504x over previous
//
#include <hip/hip_runtime.h>

// ---------------------------------------------------------------------------
// LRU single step, fused — v14 (v10 with natural LDS -> 3 blocks/CU).
//   state = Lambda * x0 + Bn @ u              (complex; stored PLANAR re|im)
//   y     = s_re @ C_re^T - s_im @ C_im^T + u @ D^T
//
// Ladder (main-kernel dur / FETCH+WRITE MB):
//  v2 192/196. v3 frag-I/O BAD. v4 268/426: 4 blk/CU window(320MB)>L3 BAD.
//  v5/v6 window BAD. v7 195/196. v8 reg-pipe NULL. v9 fusion REGRESS.
//  v10 176/189 WIN (nt-loads). v11 rotation+setprio NULL.
//  v12 ROWS=16 REGRESS. v13 split: S=129us @3blk/CU VGPR40 FETCH 96MB --
//  proves 3 blk/CU (246MB window) does NOT thrash; standalone Y ~100us
//  (1blk/CU) makes split net loss -> fused does y for ~47us incremental.
// v14: v10 exactly, minus the v7 LDS pad that pinned 2 blk/CU. Natural
//  footprint Xu+Sc0+Sc1 = 50,688B -> 3 blocks/CU (24 waves). Single change.
// Kept: nt-loads, linear global I/O, swapped-operand MFMA, dbuf Sc,
//  x0 prefetch one chunk ahead, launch_bounds(512,4).
// ---------------------------------------------------------------------------

typedef __attribute__((ext_vector_type(8))) short bf16x8;
typedef __attribute__((ext_vector_type(4))) float f32x4;
typedef unsigned short u16;

#define N_ROWS 32768
#define IN_DIM 256
#define SD 512
#define OUT_DIM 256
#define ROWS 32          // rows (n) per block
#define NTHR 512         // 8 waves
#define TP 264           // tile pitch in u16 (256 + 8 pad)
#define YP 260           // y staging pitch in f32
#define SMEM_U16 (3 * ROWS * TP)   // 50,688 B -> 3 blocks/CU (v13-S proven)

#define MFMA16(a, b, c) __builtin_amdgcn_mfma_f32_16x16x32_bf16(a, b, c, 0, 0, 0)

__device__ __align__(16) float g_lam[2 * SD];            // lam_re | lam_im
__device__ __align__(16) u16   g_W1[1024 * IN_DIM];      // bf16
__device__ __align__(16) u16   g_Wy[OUT_DIM * 1280];     // bf16

__device__ __forceinline__ u16 f2b(float f) {
    union { float f; unsigned int u; } v; v.f = f;
    unsigned int r = v.u + 0x7FFFu + ((v.u >> 16) & 1u);   // RNE
    return (u16)(r >> 16);
}
__device__ __forceinline__ ushort4 f2b4(f32x4 v) {
    ushort4 b;
    b.x = f2b(v[0]); b.y = f2b(v[1]); b.z = f2b(v[2]); b.w = f2b(v[3]);
    return b;
}
__device__ __forceinline__ f32x4 b2f4(ushort4 b) {
    union { float f; unsigned int u; } t0, t1, t2, t3;
    t0.u = (unsigned)b.x << 16; t1.u = (unsigned)b.y << 16;
    t2.u = (unsigned)b.z << 16; t3.u = (unsigned)b.w << 16;
    return f32x4{t0.f, t1.f, t2.f, t3.f};
}

// --- combined prep (single launch) -----------------------------------------
__global__ void prep_all(const float* __restrict__ nu_log,
                         const float* __restrict__ theta_log,
                         const float* __restrict__ gamma_log,
                         const float* __restrict__ B_re, const float* __restrict__ B_im,
                         const float* __restrict__ C_re, const float* __restrict__ C_im,
                         const float* __restrict__ D) {
    int b = blockIdx.x, t = threadIdx.x;
    if (b < 1024) {
        int w = b & 255;
        int h = (b >> 8) * 128 + (w & 127);
        float g = expf(gamma_log[h]);
        const float* src = (w < 128) ? B_re : B_im;
        g_W1[b * IN_DIM + t] = f2b(src[h * IN_DIM + t] * g);
    } else if (b < 1280) {
        // Wy chunked: cols s*256+[0,128)=C_re[o][s*128+j],
        //             cols s*256+[128,256)=-C_im[o][s*128+j], [1024,1280)=D
        int o = b - 1024;
        #pragma unroll
        for (int it = 0; it < 5; ++it) {
            int c = it * 256 + t;
            float v;
            if (c < 1024) {
                int s = c >> 8, k = c & 255;
                v = (k < 128) ? C_re[o * SD + s * 128 + k]
                              : -C_im[o * SD + s * 128 + (k - 128)];
            } else {
                v = D[o * IN_DIM + (c - 1024)];
            }
            g_Wy[(size_t)o * 1280 + c] = f2b(v);
        }
    } else {
        int h = (b - 1280) * 256 + t;          // [0,512)
        float mod = expf(-expf(nu_log[h]));
        float th  = expf(theta_log[h]);
        g_lam[h]      = mod * cosf(th);
        g_lam[SD + h] = mod * sinf(th);
    }
}

// --- main fused kernel ------------------------------------------------------
__global__ __launch_bounds__(NTHR, 4) void lru_main(
    const float* __restrict__ u, const float* __restrict__ x0_re,
    const float* __restrict__ x0_im,
    float* __restrict__ y_out, float* __restrict__ st_out,
    long long st_limit)     // floats available in the state region of d_out
{
    __shared__ __align__(16) u16 SMEM[SMEM_U16];   // 50,688 B -> 3 blk/CU

    u16* Xu  = SMEM;                  // u tile bf16 [32][TP]
    u16* Sc0 = SMEM + ROWS * TP;      // state chunk bf16, ping
    u16* Sc1 = SMEM + 2 * ROWS * TP;  // state chunk bf16, pong

    const int tid  = threadIdx.x;
    const int wv   = tid >> 6;          // [0,8)
    const int lane = tid & 63;
    const int quad = lane >> 4;
    const int l16  = lane & 15;
    const int kq   = quad * 8;
    const size_t n0 = (size_t)blockIdx.x * ROWS;

    const int Mb = wv * 32;             // wave's M base within a 256-col chunk

    // linear epilogue / prefetch mapping: 1024 slots (32 rows x 32 j4)
    int en[2], ej[2];
    #pragma unroll
    for (int it = 0; it < 2; ++it) {
        int flat = it * NTHR + tid;
        en[it] = flat >> 5; ej[it] = flat & 31;
    }

    // prefetch x0 chunk 0 (nt: evict-first, don't thrash weight lines)
    f32x4 xr[2], xi[2];
    #pragma unroll
    for (int it = 0; it < 2; ++it) {
        size_t roff = (n0 + en[it]) * SD + ej[it] * 4;
        xr[it] = __builtin_nontemporal_load((const f32x4*)(x0_re + roff));
        xi[it] = __builtin_nontemporal_load((const f32x4*)(x0_im + roff));
    }

    // stage u tile -> bf16 LDS (32x256, linear nt f32x4 loads)
    #pragma unroll
    for (int i = 0; i < 4; ++i) {
        int it = tid + i * NTHR;              // 2048 items
        int r = it >> 6, c4 = it & 63;
        f32x4 v = __builtin_nontemporal_load(
            (const f32x4*)(u + (n0 + r) * IN_DIM) + c4);
        *(ushort4*)(&Xu[r * TP + c4 * 4]) = f2b4(v);
    }
    __syncthreads();

    f32x4 accy[2][2];
    #pragma unroll
    for (int ot = 0; ot < 2; ++ot)
        #pragma unroll
        for (int nt = 0; nt < 2; ++nt)
            accy[ot][nt] = f32x4{0.f, 0.f, 0.f, 0.f};

    for (int s = 0; s < 4; ++s) {
        u16* Sc = (s & 1) ? Sc1 : Sc0;        // double buffer

        // ---- GEMM-A (swapped): Bu[M=256(re|im)][n=32] = W1_chunk @ Xu^T
        f32x4 acc[2][2];
        #pragma unroll
        for (int ht = 0; ht < 2; ++ht)
            #pragma unroll
            for (int nt = 0; nt < 2; ++nt)
                acc[ht][nt] = f32x4{0.f, 0.f, 0.f, 0.f};
        const u16* w1b = g_W1 + (size_t)(s * 256 + Mb) * IN_DIM;
        #pragma unroll
        for (int k0 = 0; k0 < IN_DIM; k0 += 32) {
            bf16x8 a[2], b[2];
            #pragma unroll
            for (int ht = 0; ht < 2; ++ht)
                a[ht] = *(const bf16x8*)(w1b + (ht * 16 + l16) * IN_DIM + k0 + kq);
            #pragma unroll
            for (int nt = 0; nt < 2; ++nt)
                b[nt] = *(const bf16x8*)(&Xu[(nt * 16 + l16) * TP + k0 + kq]);
            #pragma unroll
            for (int ht = 0; ht < 2; ++ht)
                #pragma unroll
                for (int nt = 0; nt < 2; ++nt)
                    acc[ht][nt] = MFMA16(a[ht], b[nt], acc[ht][nt]);
        }
        // fragments -> Sc as bf16 (contiguous ushort4: lane owns 4 consec h)
        #pragma unroll
        for (int ht = 0; ht < 2; ++ht)
            #pragma unroll
            for (int nt = 0; nt < 2; ++nt) {
                const int n  = nt * 16 + l16;
                const int hM = Mb + ht * 16 + quad * 4;
                *(ushort4*)(&Sc[n * TP + hM]) = f2b4(acc[ht][nt]);
            }
        __syncthreads();            // barrier A: Sc (Bu bf16) complete

        // ---- linear epilogue: in-place Sc update + contiguous f32 stores
        #pragma unroll
        for (int it = 0; it < 2; ++it) {
            const int n = en[it], j = ej[it];
            f32x4 br  = b2f4(*(const ushort4*)(&Sc[n * TP + j * 4]));
            f32x4 bi  = b2f4(*(const ushort4*)(&Sc[n * TP + 128 + j * 4]));
            f32x4 lre = *(const f32x4*)(g_lam + s * 128 + j * 4);
            f32x4 lim = *(const f32x4*)(g_lam + SD + s * 128 + j * 4);
            f32x4 sr = lre * xr[it] - lim * xi[it] + br;
            f32x4 si = lre * xi[it] + lim * xr[it] + bi;
            const long long ir = (long long)((n0 + n) * SD + s * 128 + j * 4);
            const long long ii = (long long)N_ROWS * SD + ir;
            if (ir + 3 < st_limit) {
                *(f32x4*)(st_out + ir) = sr;       // cacheable: L3 absorbs
            } else {
                #pragma unroll
                for (int k = 0; k < 4; ++k)
                    if (ir + k < st_limit) st_out[ir + k] = sr[k];
            }
            if (ii + 3 < st_limit) {
                *(f32x4*)(st_out + ii) = si;
            } else {
                #pragma unroll
                for (int k = 0; k < 4; ++k)
                    if (ii + k < st_limit) st_out[ii + k] = si[k];
            }
            *(ushort4*)(&Sc[n * TP + j * 4])       = f2b4(sr);
            *(ushort4*)(&Sc[n * TP + 128 + j * 4]) = f2b4(si);
        }

        // prefetch x0 for next chunk BEFORE barrier B (nt): latency rides
        // under barrier + y-GEMM + next GEMM-A.
        if (s < 3) {
            #pragma unroll
            for (int it = 0; it < 2; ++it) {
                size_t roff = (n0 + en[it]) * SD + (s + 1) * 128 + ej[it] * 4;
                xr[it] = __builtin_nontemporal_load((const f32x4*)(x0_re + roff));
                xi[it] = __builtin_nontemporal_load((const f32x4*)(x0_im + roff));
            }
        }
        __syncthreads();            // barrier B: Sc now bf16 state chunk

        // ---- partial y-GEMM (swapped): accy += Wy_chunk @ Sc^T
        // (no barrier after: next chunk writes the OTHER Sc buffer)
        #pragma unroll
        for (int k0 = 0; k0 < 256; k0 += 32) {
            bf16x8 a[2], b[2];
            #pragma unroll
            for (int ot = 0; ot < 2; ++ot)
                a[ot] = *(const bf16x8*)(g_Wy + (size_t)(Mb + ot * 16 + l16) * 1280
                                         + s * 256 + k0 + kq);
            #pragma unroll
            for (int nt = 0; nt < 2; ++nt)
                b[nt] = *(const bf16x8*)(&Sc[(nt * 16 + l16) * TP + k0 + kq]);
            #pragma unroll
            for (int ot = 0; ot < 2; ++ot)
                #pragma unroll
                for (int nt = 0; nt < 2; ++nt)
                    accy[ot][nt] = MFMA16(a[ot], b[nt], accy[ot][nt]);
        }
    }

    // ---- y u-part: accy += D @ Xu^T
    #pragma unroll
    for (int k0 = 0; k0 < IN_DIM; k0 += 32) {
        bf16x8 a[2], b[2];
        #pragma unroll
        for (int ot = 0; ot < 2; ++ot)
            a[ot] = *(const bf16x8*)(g_Wy + (size_t)(Mb + ot * 16 + l16) * 1280
                                     + 1024 + k0 + kq);
        #pragma unroll
        for (int nt = 0; nt < 2; ++nt)
            b[nt] = *(const bf16x8*)(&Xu[(nt * 16 + l16) * TP + k0 + kq]);
        #pragma unroll
        for (int ot = 0; ot < 2; ++ot)
            #pragma unroll
            for (int nt = 0; nt < 2; ++nt)
                accy[ot][nt] = MFMA16(a[ot], b[nt], accy[ot][nt]);
    }

    // ---- y: fragments -> f32 LDS (all tiles dead) -> linear store
    __syncthreads();                // everyone done reading Xu/Sc0/Sc1
    float* Yf = (float*)SMEM;       // [32][YP]  (32*260*4 = 33,280 <= 50,688)
    #pragma unroll
    for (int ot = 0; ot < 2; ++ot)
        #pragma unroll
        for (int nt = 0; nt < 2; ++nt) {
            const int n   = nt * 16 + l16;
            const int col = Mb + ot * 16 + quad * 4;
            *(f32x4*)(&Yf[n * YP + col]) = accy[ot][nt];
        }
    __syncthreads();
    #pragma unroll
    for (int i = 0; i < 4; ++i) {
        int it = tid + i * NTHR;                  // 2048 items
        int r = it >> 6, c4 = it & 63;
        f32x4 v = *(const f32x4*)(&Yf[r * YP + c4 * 4]);
        *(f32x4*)(y_out + (n0 + r) * OUT_DIM + c4 * 4) = v;
    }
}

extern "C" void kernel_launch(void* const* d_in, const int* in_sizes, int n_in,
                              void* d_out, int out_size, void* d_ws, size_t ws_size,
                              hipStream_t stream) {
    const float* u         = (const float*)d_in[0];
    const float* x0_re     = (const float*)d_in[1];
    const float* x0_im     = (const float*)d_in[2];
    const float* nu_log    = (const float*)d_in[3];
    const float* theta_log = (const float*)d_in[4];
    const float* gamma_log = (const float*)d_in[5];
    const float* B_re      = (const float*)d_in[6];
    const float* B_im      = (const float*)d_in[7];
    const float* C_re      = (const float*)d_in[8];
    const float* C_im      = (const float*)d_in[9];
    const float* D         = (const float*)d_in[10];

    float* y_out  = (float*)d_out;
    float* st_out = y_out + (size_t)N_ROWS * OUT_DIM;
    long long st_limit = (long long)out_size - (long long)N_ROWS * OUT_DIM;

    prep_all<<<1282, 256, 0, stream>>>(nu_log, theta_log, gamma_log,
                                       B_re, B_im, C_re, C_im, D);
    lru_main<<<N_ROWS / ROWS, NTHR, 0, stream>>>(u, x0_re, x0_im,
                                                 y_out, st_out, st_limit);
}